// Round 6
// baseline (104.289 us; speedup 1.0000x reference)
//
#include <hip/hip_runtime.h>
#include <hip/hip_fp16.h>
#include <math.h>

#define N_DENSE 13
#define N_SPARSE 26
#define SPARSE_DIM 100
#define N_FIELD 39               // 13 + 26 real fields
#define N_FIELD_P 40             // padded (field 39 = zeros)
#define KDIM 16
#define N_FEATURES 2613          // 13 + 26*100
#define ROW_F 624                // real elements per feature row (39*16)
#define ROW_DW 320               // padded half2 per row (40 fields * 8 k-pairs)
#define THREADS 256
#define ROWS_PER_BLOCK 4         // one 64-lane wave per row per iteration
#define GRID_BLOCKS 2048         // persistent; 8192 rows/pass, 2 passes at B=16384

// ---------------- pre-pass: fp32 -> half2, padded to 40 fields --------------
__global__ __launch_bounds__(ROW_DW) void cvt_pad_f16(
    const float* __restrict__ v, __half2* __restrict__ o)
{
    int n = blockIdx.x;
    int d = threadIdx.x;
    __half2 r = __floats2half2_rn(0.f, 0.f);
    if (d < ROW_F / 2) {
        float2 f = *reinterpret_cast<const float2*>(v + (size_t)n * ROW_F + 2 * d);
        r = __floats2half2_rn(f.x, f.y);
    }
    o[(size_t)n * ROW_DW + d] = r;
}

// ---------------- main kernel: one wave per batch row, persistent -----------
// Row image: 320 half2; element d = (field f = d>>3, k-pair j = d&7).
// Lane l owns d = l + 64m (m=0..4): exactly 5 half2, all with j = l&7.
// xor-orbit {8,16,32} of lane l = the 8 lanes with same j, covering all 40
// fields once -> after stage-1 shuffles every lane holds S(j),Q(j); the lin
// lane-terms reduce alongside. Stage-2 {1,2,4} sums the 8 j-groups.
__global__ __launch_bounds__(THREADS, 8) void ffm_f16s(
    const float* __restrict__ x,     // [B, 39]
    const float* __restrict__ w,     // [2613]
    const float* __restrict__ bias,  // [1]
    const __half2* __restrict__ vb,  // [2613, 320] padded half2 rows
    float* __restrict__ out,         // [B]
    int B)
{
    __shared__ __half2 ldsDense[N_DENSE * ROW_DW];   // 16640 B
    {
        const uint4* src = reinterpret_cast<const uint4*>(vb);
        uint4* dst = reinterpret_cast<uint4*>(ldsDense);
        for (int i = threadIdx.x; i < N_DENSE * ROW_DW / 4; i += THREADS)
            dst[i] = src[i];
    }
    __syncthreads();

    const int l = threadIdx.x & 63;
    // wave-uniform wave id -> uniform row -> x reads become s_loads
    const int wv = __builtin_amdgcn_readfirstlane((int)(threadIdx.x >> 6));
    const float b0 = bias[0];

    for (int row = blockIdx.x * ROWS_PER_BLOCK + wv; row < B;
         row += GRID_BLOCKS * ROWS_PER_BLOCK) {

        const float* xr = x + (size_t)row * N_FIELD;

        // ---- per-lane linear-part term (folded into the reduction later) ----
        float xv_l = 0.f;
        if (l < N_FIELD) xv_l = xr[l];
        float linp = 0.f;
        if (l < N_DENSE) {
            linp = xv_l * w[l];
        } else if (l < N_FIELD) {
            int idx = N_DENSE + (l - N_DENSE) * SPARSE_DIM + (int)xv_l;
            linp = w[idx];
        }

        __half2 acc[5];
#pragma unroll
        for (int m = 0; m < 5; ++m) acc[m] = __floats2half2_rn(0.f, 0.f);

        // ---- dense features (LDS broadcast, uniform xv) ----
#pragma unroll
        for (int j = 0; j < N_DENSE; ++j) {
            __half2 xh = __float2half2_rn(xr[j]);
#pragma unroll
            for (int m = 0; m < 5; ++m)
                acc[m] = __hfma2(xh, ldsDense[j * ROW_DW + 64 * m + l], acc[m]);
        }

        // ---- sparse gathers: scalar base per feature, 5 dword loads ----
#pragma unroll
        for (int s = 0; s < N_SPARSE; ++s) {
            int su = __builtin_amdgcn_readfirstlane((int)xr[N_DENSE + s]);
            const __half2* b =
                vb + (size_t)(N_DENSE + s * SPARSE_DIM + su) * ROW_DW + l;
            acc[0] = __hadd2(acc[0], b[0]);
            acc[1] = __hadd2(acc[1], b[64]);
            acc[2] = __hadd2(acc[2], b[128]);
            acc[3] = __hadd2(acc[3], b[192]);
            acc[4] = __hadd2(acc[4], b[256]);
        }

        // ---- reduction (f32) ----
        float sx = 0.f, sy = 0.f, qx = 0.f, qy = 0.f;
#pragma unroll
        for (int m = 0; m < 5; ++m) {
            float ax = __low2float(acc[m]);
            float ay = __high2float(acc[m]);
            sx += ax; sy += ay;
            qx = fmaf(ax, ax, qx);
            qy = fmaf(ay, ay, qy);
        }
        // stage 1: sum over the 8 lanes sharing this j (and lin partial)
#pragma unroll
        for (int mask = 8; mask <= 32; mask <<= 1) {
            sx   += __shfl_xor(sx, mask);
            sy   += __shfl_xor(sy, mask);
            qx   += __shfl_xor(qx, mask);
            qy   += __shfl_xor(qy, mask);
            linp += __shfl_xor(linp, mask);
        }
        // per-lane: half cross-term for j = l&7, plus lin residue-partial
        float u = 0.5f * ((sx * sx - qx) + (sy * sy - qy)) + linp;
        // stage 2: sum the 8 j-groups
        u += __shfl_xor(u, 1);
        u += __shfl_xor(u, 2);
        u += __shfl_xor(u, 4);

        float logit = b0 + u;
        if (l == 0) out[row] = 1.f / (1.f + expf(-logit));
    }
}

// ---------------- fp32 fallback (round-1 kernel, 16 lanes/row) --------------
#define ROW_Q (ROW_F / 4)
__global__ __launch_bounds__(256) void ffm_fp32(
    const float* __restrict__ x, const float* __restrict__ w,
    const float* __restrict__ bias, const float* __restrict__ v,
    float* __restrict__ out, int B)
{
    __shared__ float ldsDense[N_DENSE * ROW_F];
    const float4* v4 = reinterpret_cast<const float4*>(v);
    float4* lds4 = reinterpret_cast<float4*>(ldsDense);
    for (int i = threadIdx.x; i < N_DENSE * ROW_Q; i += 256) lds4[i] = v4[i];
    __syncthreads();

    const int g = threadIdx.x >> 4, l = threadIdx.x & 15;
    const int row = blockIdx.x * 16 + g;
    if (row >= B) return;
    const float* xr = x + row * (N_DENSE + N_SPARSE);

    float4 acc[10];
#pragma unroll
    for (int i = 0; i < 10; ++i) acc[i] = make_float4(0.f, 0.f, 0.f, 0.f);
#pragma unroll
    for (int j = 0; j < N_DENSE; ++j) {
        float xv = xr[j];
        const float4* b = lds4 + j * ROW_Q;
#pragma unroll
        for (int i = 0; i < 10; ++i)
            if (i < 9 || l < 12) {
                float4 t = b[l + 16 * i];
                acc[i].x += xv * t.x; acc[i].y += xv * t.y;
                acc[i].z += xv * t.z; acc[i].w += xv * t.w;
            }
    }
    int nidx[N_SPARSE];
#pragma unroll
    for (int s = 0; s < N_SPARSE; ++s)
        nidx[s] = N_DENSE + s * SPARSE_DIM + (int)xr[N_DENSE + s];
    for (int s = 0; s < N_SPARSE; ++s) {
        const float4* b = v4 + (size_t)nidx[s] * ROW_Q;
#pragma unroll
        for (int i = 0; i < 10; ++i)
            if (i < 9 || l < 12) {
                float4 t = b[l + 16 * i];
                acc[i].x += t.x; acc[i].y += t.y; acc[i].z += t.z; acc[i].w += t.w;
            }
    }
    float4 s4 = make_float4(0,0,0,0), q4 = make_float4(0,0,0,0);
#pragma unroll
    for (int i = 0; i < 10; ++i) {
        s4.x += acc[i].x; s4.y += acc[i].y; s4.z += acc[i].z; s4.w += acc[i].w;
        q4.x += acc[i].x*acc[i].x; q4.y += acc[i].y*acc[i].y;
        q4.z += acc[i].z*acc[i].z; q4.w += acc[i].w*acc[i].w;
    }
#pragma unroll
    for (int m = 4; m <= 8; m <<= 1) {
        s4.x += __shfl_xor(s4.x,m); s4.y += __shfl_xor(s4.y,m);
        s4.z += __shfl_xor(s4.z,m); s4.w += __shfl_xor(s4.w,m);
        q4.x += __shfl_xor(q4.x,m); q4.y += __shfl_xor(q4.y,m);
        q4.z += __shfl_xor(q4.z,m); q4.w += __shfl_xor(q4.w,m);
    }
    float c = (s4.x*s4.x - q4.x) + (s4.y*s4.y - q4.y) +
              (s4.z*s4.z - q4.z) + (s4.w*s4.w - q4.w);
    c += __shfl_xor(c,1); c += __shfl_xor(c,2);
    float lin = bias[0];
#pragma unroll
    for (int j = 0; j < N_DENSE; ++j) lin += xr[j]*w[j];
#pragma unroll
    for (int s = 0; s < N_SPARSE; ++s) lin += w[nidx[s]];
    float logit = lin + 0.5f*c;
    if (l == 0) out[row] = 1.f/(1.f+expf(-logit));
}

extern "C" void kernel_launch(void* const* d_in, const int* in_sizes, int n_in,
                              void* d_out, int out_size, void* d_ws, size_t ws_size,
                              hipStream_t stream) {
    const float* x    = (const float*)d_in[0];
    const float* w    = (const float*)d_in[1];
    const float* bias = (const float*)d_in[2];
    const float* v    = (const float*)d_in[3];
    float* out = (float*)d_out;

    int B = in_sizes[0] / (N_DENSE + N_SPARSE);
    size_t need = (size_t)N_FEATURES * ROW_DW * sizeof(__half2);  // 3,344,640 B

    if (ws_size >= need) {
        cvt_pad_f16<<<N_FEATURES, ROW_DW, 0, stream>>>(v, (__half2*)d_ws);
        ffm_f16s<<<GRID_BLOCKS, THREADS, 0, stream>>>(
            x, w, bias, (const __half2*)d_ws, out, B);
    } else {
        int grid = (B + 15) / 16;
        ffm_fp32<<<grid, 256, 0, stream>>>(x, w, bias, v, out, B);
    }
}

// Round 7
// 53.480 us; speedup vs baseline: 1.9501x; 1.9501x over previous
//
#include <hip/hip_runtime.h>
#include <hip/hip_fp16.h>
#include <math.h>

#define N_DENSE 13
#define N_SPARSE 26
#define SPARSE_DIM 100
#define N_FIELD 39               // 13 + 26 real fields
#define KDIM 16
#define N_FEATURES 2613          // 13 + 26*100
#define ROW_F 624                // real elements per feature row (39*16)
#define ROW_DW 320               // padded half2 per row (40 fields * 8 k-pairs)
#define ROW_BYTES 1280
#define THREADS 256
#define ROWS_PER_BLOCK 4         // one 64-lane wave per row

// ---------------- pre-pass: fp32 -> half2, padded to 40 fields --------------
__global__ __launch_bounds__(ROW_DW) void cvt_pad_f16(
    const float* __restrict__ v, __half2* __restrict__ o)
{
    int n = blockIdx.x;
    int d = threadIdx.x;
    __half2 r = __floats2half2_rn(0.f, 0.f);
    if (d < ROW_F / 2) {
        float2 f = *reinterpret_cast<const float2*>(v + (size_t)n * ROW_F + 2 * d);
        r = __floats2half2_rn(f.x, f.y);
    }
    o[(size_t)n * ROW_DW + d] = r;
}

__device__ __forceinline__ __half2 h2(unsigned int v) {
    return *reinterpret_cast<__half2*>(&v);
}

// ---------------- main kernel: one wave per batch row -----------------------
// Row image: 320 dwords (half2); dword d = (field f = d>>3, k-pair j = d&7).
// Lane l (p=l&3, t=l>>2):
//   load1 uint2 @ dword 2l        -> field t,    k = 4p..4p+3   (accP0, accP1)
//   load2 uint2 @ dword 128+2l    -> field 16+t, k = 4p..4p+3   (accQ0, accQ1)
//   loadB dword @ 256+(t>>1)*8+2p+(t&1) -> field 32+(t>>1), k = 4p+2u,+1 (accB)
// xor-orbit {4,8,16,32} of lane l = 16 lanes with same p, covering all 40
// fields exactly once per k in 4p..4p+3. Stage-2 {1,2} merges the 4 p-classes.
// The per-lane linear-part term rides the same shuffles ({4..32} then {1,2}).
__global__ __launch_bounds__(THREADS, 8) void ffm_v7(
    const float* __restrict__ x,     // [B, 39]
    const float* __restrict__ w,     // [2613]
    const float* __restrict__ bias,  // [1]
    const __half2* __restrict__ vb,  // [2613, 320] padded half2 rows
    float* __restrict__ out,         // [B]
    int B)
{
    __shared__ __half2 ldsDense[N_DENSE * ROW_DW];   // 16640 B
    {
        const uint4* src = reinterpret_cast<const uint4*>(vb);
        uint4* dst = reinterpret_cast<uint4*>(ldsDense);
        for (int i = threadIdx.x; i < N_DENSE * ROW_DW / 4; i += THREADS)
            dst[i] = src[i];
    }
    __syncthreads();

    const int l = threadIdx.x & 63;
    const int p = l & 3;
    const int t = l >> 2;
    const int u = t & 1;
    const int row = blockIdx.x * ROWS_PER_BLOCK + (threadIdx.x >> 6);
    if (row >= B) return;

    const float b0v = bias[0];

    // ---- one x-row load: lane t<39 holds x[row,t] ----
    float xv = 0.f;
    if (l < N_FIELD) xv = x[(size_t)row * N_FIELD + l];
    int idx = 0;
    if (l >= N_DENSE && l < N_FIELD)
        idx = N_DENSE + (l - N_DENSE) * SPARSE_DIM + (int)xv;

    // ---- per-lane linear-part term (single gather) ----
    float linp = 0.f;
    if (l < N_FIELD) {
        float wv = w[l < N_DENSE ? l : idx];
        linp = (l < N_DENSE) ? xv * wv : wv;
    }

    // lane-local byte offsets within a row
    const int o1 = 8 * l;                                  // load1
    const int o2 = 512 + 8 * l;                            // load2
    const int oB = 1024 + ((t >> 1) << 5) + (p << 3) + (u << 2);
    const int dB = oB >> 2;                                // dword index (LDS)

    __half2 zero = __floats2half2_rn(0.f, 0.f);
    __half2 aP0 = zero, aP1 = zero, aQ0 = zero, aQ1 = zero, aB = zero;

    // ---- dense features (LDS, x broadcast by shuffle) ----
#pragma unroll
    for (int j = 0; j < N_DENSE; ++j) {
        float xj = __shfl(xv, j);
        __half2 xh = __float2half2_rn(xj);
        const uint2* b64 = reinterpret_cast<const uint2*>(ldsDense + j * ROW_DW);
        uint2 d1 = b64[l];
        uint2 d2 = b64[64 + l];
        unsigned int dB32 =
            reinterpret_cast<const unsigned int*>(ldsDense + j * ROW_DW)[dB];
        aP0 = __hfma2(xh, h2(d1.x), aP0);
        aP1 = __hfma2(xh, h2(d1.y), aP1);
        aQ0 = __hfma2(xh, h2(d2.x), aQ0);
        aQ1 = __hfma2(xh, h2(d2.y), aQ1);
        aB  = __hfma2(xh, h2(dB32), aB);
    }

    // ---- sparse gathers: index broadcast by shuffle, 3 wide loads/feature ----
#pragma unroll
    for (int s = 0; s < N_SPARSE; s += 2) {
        int i0 = __shfl(idx, N_DENSE + s);
        int i1 = __shfl(idx, N_DENSE + s + 1);
        const char* r0 = reinterpret_cast<const char*>(vb) + (size_t)i0 * ROW_BYTES;
        const char* r1 = reinterpret_cast<const char*>(vb) + (size_t)i1 * ROW_BYTES;
        uint2 a0 = *reinterpret_cast<const uint2*>(r0 + o1);
        uint2 c0 = *reinterpret_cast<const uint2*>(r0 + o2);
        unsigned int e0 = *reinterpret_cast<const unsigned int*>(r0 + oB);
        uint2 a1 = *reinterpret_cast<const uint2*>(r1 + o1);
        uint2 c1 = *reinterpret_cast<const uint2*>(r1 + o2);
        unsigned int e1 = *reinterpret_cast<const unsigned int*>(r1 + oB);
        aP0 = __hadd2(aP0, h2(a0.x)); aP1 = __hadd2(aP1, h2(a0.y));
        aQ0 = __hadd2(aQ0, h2(c0.x)); aQ1 = __hadd2(aQ1, h2(c0.y));
        aB  = __hadd2(aB,  h2(e0));
        aP0 = __hadd2(aP0, h2(a1.x)); aP1 = __hadd2(aP1, h2(a1.y));
        aQ0 = __hadd2(aQ0, h2(c1.x)); aQ1 = __hadd2(aQ1, h2(c1.y));
        aB  = __hadd2(aB,  h2(e1));
    }

    // ---- unpack to f32; merge part B into its k-slots (branchless) ----
    float fP[4] = { __low2float(aP0), __high2float(aP0),
                    __low2float(aP1), __high2float(aP1) };
    float fQ[4] = { __low2float(aQ0), __high2float(aQ0),
                    __low2float(aQ1), __high2float(aQ1) };
    float bb0 = __low2float(aB), bb1 = __high2float(aB);
    float e0 = u ? 0.f : bb0, e1 = u ? 0.f : bb1;
    float e2 = u ? bb0 : 0.f, e3 = u ? bb1 : 0.f;

    float s0 = fP[0] + fQ[0] + e0;
    float s1 = fP[1] + fQ[1] + e1;
    float s2 = fP[2] + fQ[2] + e2;
    float s3 = fP[3] + fQ[3] + e3;
    float q0 = fP[0]*fP[0] + fQ[0]*fQ[0] + e0*e0;
    float q1 = fP[1]*fP[1] + fQ[1]*fQ[1] + e1*e1;
    float q2 = fP[2]*fP[2] + fQ[2]*fQ[2] + e2*e2;
    float q3 = fP[3]*fP[3] + fQ[3]*fQ[3] + e3*e3;

    // ---- stage 1: sum over the 16-lane orbit (same p) + linp rides along ----
#pragma unroll
    for (int m = 4; m <= 32; m <<= 1) {
        s0 += __shfl_xor(s0, m); s1 += __shfl_xor(s1, m);
        s2 += __shfl_xor(s2, m); s3 += __shfl_xor(s3, m);
        q0 += __shfl_xor(q0, m); q1 += __shfl_xor(q1, m);
        q2 += __shfl_xor(q2, m); q3 += __shfl_xor(q3, m);
        linp += __shfl_xor(linp, m);
    }
    float cpart = (s0*s0 - q0) + (s1*s1 - q1) + (s2*s2 - q2) + (s3*s3 - q3);
    float uval = 0.5f * cpart + linp;
    // ---- stage 2: merge the 4 p-classes (and finish linp) ----
    uval += __shfl_xor(uval, 1);
    uval += __shfl_xor(uval, 2);

    float logit = b0v + uval;
    if (l == 0) out[row] = 1.f / (1.f + expf(-logit));
}

// ---------------- fp32 fallback (round-1 kernel, 16 lanes/row) --------------
#define ROW_Q (ROW_F / 4)
__global__ __launch_bounds__(256) void ffm_fp32(
    const float* __restrict__ x, const float* __restrict__ w,
    const float* __restrict__ bias, const float* __restrict__ v,
    float* __restrict__ out, int B)
{
    __shared__ float ldsDense[N_DENSE * ROW_F];
    const float4* v4 = reinterpret_cast<const float4*>(v);
    float4* lds4 = reinterpret_cast<float4*>(ldsDense);
    for (int i = threadIdx.x; i < N_DENSE * ROW_Q; i += 256) lds4[i] = v4[i];
    __syncthreads();

    const int g = threadIdx.x >> 4, l = threadIdx.x & 15;
    const int row = blockIdx.x * 16 + g;
    if (row >= B) return;
    const float* xr = x + row * (N_DENSE + N_SPARSE);

    float4 acc[10];
#pragma unroll
    for (int i = 0; i < 10; ++i) acc[i] = make_float4(0.f, 0.f, 0.f, 0.f);
#pragma unroll
    for (int j = 0; j < N_DENSE; ++j) {
        float xv = xr[j];
        const float4* b = lds4 + j * ROW_Q;
#pragma unroll
        for (int i = 0; i < 10; ++i)
            if (i < 9 || l < 12) {
                float4 tt = b[l + 16 * i];
                acc[i].x += xv * tt.x; acc[i].y += xv * tt.y;
                acc[i].z += xv * tt.z; acc[i].w += xv * tt.w;
            }
    }
    int nidx[N_SPARSE];
#pragma unroll
    for (int s = 0; s < N_SPARSE; ++s)
        nidx[s] = N_DENSE + s * SPARSE_DIM + (int)xr[N_DENSE + s];
    for (int s = 0; s < N_SPARSE; ++s) {
        const float4* b = v4 + (size_t)nidx[s] * ROW_Q;
#pragma unroll
        for (int i = 0; i < 10; ++i)
            if (i < 9 || l < 12) {
                float4 tt = b[l + 16 * i];
                acc[i].x += tt.x; acc[i].y += tt.y; acc[i].z += tt.z; acc[i].w += tt.w;
            }
    }
    float4 s4 = make_float4(0,0,0,0), q4 = make_float4(0,0,0,0);
#pragma unroll
    for (int i = 0; i < 10; ++i) {
        s4.x += acc[i].x; s4.y += acc[i].y; s4.z += acc[i].z; s4.w += acc[i].w;
        q4.x += acc[i].x*acc[i].x; q4.y += acc[i].y*acc[i].y;
        q4.z += acc[i].z*acc[i].z; q4.w += acc[i].w*acc[i].w;
    }
#pragma unroll
    for (int m = 4; m <= 8; m <<= 1) {
        s4.x += __shfl_xor(s4.x,m); s4.y += __shfl_xor(s4.y,m);
        s4.z += __shfl_xor(s4.z,m); s4.w += __shfl_xor(s4.w,m);
        q4.x += __shfl_xor(q4.x,m); q4.y += __shfl_xor(q4.y,m);
        q4.z += __shfl_xor(q4.z,m); q4.w += __shfl_xor(q4.w,m);
    }
    float c = (s4.x*s4.x - q4.x) + (s4.y*s4.y - q4.y) +
              (s4.z*s4.z - q4.z) + (s4.w*s4.w - q4.w);
    c += __shfl_xor(c,1); c += __shfl_xor(c,2);
    float lin = bias[0];
#pragma unroll
    for (int j = 0; j < N_DENSE; ++j) lin += xr[j]*w[j];
#pragma unroll
    for (int s = 0; s < N_SPARSE; ++s) lin += w[nidx[s]];
    float logit = lin + 0.5f*c;
    if (l == 0) out[row] = 1.f/(1.f+expf(-logit));
}

extern "C" void kernel_launch(void* const* d_in, const int* in_sizes, int n_in,
                              void* d_out, int out_size, void* d_ws, size_t ws_size,
                              hipStream_t stream) {
    const float* x    = (const float*)d_in[0];
    const float* w    = (const float*)d_in[1];
    const float* bias = (const float*)d_in[2];
    const float* v    = (const float*)d_in[3];
    float* out = (float*)d_out;

    int B = in_sizes[0] / (N_DENSE + N_SPARSE);
    size_t need = (size_t)N_FEATURES * ROW_DW * sizeof(__half2);  // 3,344,640 B

    if (ws_size >= need) {
        cvt_pad_f16<<<N_FEATURES, ROW_DW, 0, stream>>>(v, (__half2*)d_ws);
        int grid = (B + ROWS_PER_BLOCK - 1) / ROWS_PER_BLOCK;
        ffm_v7<<<grid, THREADS, 0, stream>>>(
            x, w, bias, (const __half2*)d_ws, out, B);
    } else {
        int grid = (B + 15) / 16;
        ffm_fp32<<<grid, 256, 0, stream>>>(x, w, bias, v, out, B);
    }
}